// Round 6
// baseline (174.435 us; speedup 1.0000x reference)
//
#include <hip/hip_runtime.h>

#define NB 4
#define NC 6
#define NF 257
#define NT 2000
#define NG (NB * NF)        // 1028 (b,f) groups
#define NPAIR 15
#define NACC 74             // solve-side layout: [0..5] s_diag, [6..11] n_diag, [12+4q..] s_re,s_im,n_re,n_im, [72] sum_ms, [73] sum_mn
#define NACCS 37            // psd-side split layout: [0..5] diag, [6+2q],[7+2q] pair re/im, [36] mask sum
#define PSTR 40             // wsp row stride (floats)
#define NCHUNK 4
#define TCH (NT / NCHUNK)   // 500 t per chunk
#define NP2 (TCH / 2)       // 250 float2 positions per chunk
#define BLK 256
#define CS  (NF * NT)       // channel stride (floats)
#define CS2 (CS / 2)        // channel stride (float2)

typedef float nfloat4 __attribute__((ext_vector_type(4)));

// DPP row-shift-right add: lane i += lane (i-N) within its 16-lane row
// (0 beyond row edge). After shr8+shr4+shr2: lane14 = row evens-sum,
// lane15 = row odds-sum (HW-verified in prior session).
template<int CTRL>
__device__ __forceinline__ float dpp_add(float v) {
    int s = __builtin_amdgcn_update_dpp(0, __builtin_bit_cast(int, v), CTRL, 0xF, 0xF, true);
    return v + __builtin_bit_cast(float, s);
}

// ---------------- Kernel A: split-mask weighted PSD partials ----------------
// 8224 blocks = (group, chunk, parity). parity 0 -> s-mask, 1 -> n-mask.
// 37 accumulators/thread (NOT 74): VGPR ~80 -> 6 waves/SIMD (vs 3 at 132),
// double the block-level TLP. Spec is read twice through L3 (cheap); the
// scarce resource here is latency tolerance, not bandwidth or VALU.
__global__ __launch_bounds__(BLK) void psd_kernel(
    const float* __restrict__ sr, const float* __restrict__ si,
    const float* __restrict__ ms, const float* __restrict__ mn,
    float* __restrict__ wsp)
{
    constexpr int PC[NPAIR] = {0,0,0,0,0,1,1,1,1,2,2,2,3,3,4};
    constexpr int PE[NPAIR] = {1,2,3,4,5,2,3,4,5,3,4,5,4,5,5};

    const int bx     = blockIdx.x;
    const int g      = bx >> 3;
    const int rem    = bx & 7;
    const int chunk  = rem >> 1;
    const int parity = rem & 1;
    const int b  = g / NF;
    const int f  = g - b * NF;
    const int tb = chunk * TCH;
    const int sbase = b * NC * CS + f * NT + tb;
    const int mbase = g * NT + tb;

    const float2* s2r = (const float2*)(sr + sbase);
    const float2* s2i = (const float2*)(si + sbase);
    const float2* m2  = (const float2*)((parity ? mn : ms) + mbase);

    float acc[NACCS];
    #pragma unroll
    for (int i = 0; i < NACCS; i++) acc[i] = 0.f;

    // Unconditional load burst; inactive lanes load p=0 and zero their mask
    // weights (every accumulator term carries the mask factor -> contributes 0).
    const bool act = threadIdx.x < NP2;
    const int  p   = act ? threadIdx.x : 0;
    {
        float wm[2], rr[NC][2], ii[NC][2];
        {
            const float2 t0 = m2[p];
            wm[0] = t0.x; wm[1] = t0.y;
        }
        #pragma unroll
        for (int c = 0; c < NC; c++) {
            const float2 tr = s2r[c * CS2 + p];
            rr[c][0] = tr.x; rr[c][1] = tr.y;
            const float2 ti = s2i[c * CS2 + p];
            ii[c][0] = ti.x; ii[c][1] = ti.y;
        }
        if (!act) { wm[0] = wm[1] = 0.f; }
        #pragma unroll
        for (int k = 0; k < 2; k++) acc[36] += wm[k];
        #pragma unroll
        for (int c = 0; c < NC; c++) {
            #pragma unroll
            for (int k = 0; k < 2; k++) {
                const float d = rr[c][k] * rr[c][k] + ii[c][k] * ii[c][k];
                acc[c] += d * wm[k];
            }
        }
        #pragma unroll
        for (int q = 0; q < NPAIR; q++) {
            const int c = PC[q], e = PE[q];
            #pragma unroll
            for (int k = 0; k < 2; k++) {
                const float cr = rr[c][k] * rr[e][k] + ii[c][k] * ii[e][k];
                const float ci = ii[c][k] * rr[e][k] - rr[c][k] * ii[e][k];
                acc[6 + 2 * q]     += cr * wm[k];
                acc[6 + 2 * q + 1] += ci * wm[k];
            }
        }
    }

    // In-row DPP reduction (VALU pipe): lane14 = row evens-sum, lane15 = odds.
    #pragma unroll
    for (int i = 0; i < NACCS; i++) {
        float v = acc[i];
        v = dpp_add<0x118>(v);   // row_shr:8
        v = dpp_add<0x114>(v);   // row_shr:4
        v = dpp_add<0x112>(v);   // row_shr:2
        acc[i] = v;
    }

    __shared__ float red[32][NACCS];
    const int lane16 = threadIdx.x & 15;
    const int ridx   = ((threadIdx.x >> 4) << 1) | (lane16 & 1);  // 0..31
    if (lane16 >= 14) {
        #pragma unroll
        for (int i = 0; i < NACCS; i++) red[ridx][i] = acc[i];
    }
    __syncthreads();

    if (threadIdx.x < NACCS) {
        float s = 0.f;
        #pragma unroll
        for (int r = 0; r < 32; r++) s += red[r][threadIdx.x];
        wsp[bx * PSTR + threadIdx.x] = s;
    }
}

// ---------------- Kernel B: one thread per (b,f) — LU + column solves -------
// Reassembles fin[74] from the 8 split partial rows, then verbatim verified
// LU + column solves. launch_bounds(64,1): high VGPR allowed, no spills.
__global__ __launch_bounds__(64, 1) void solve_kernel(
    const float* __restrict__ wsp, float* __restrict__ wsw)
{
    const int gid = blockIdx.x * 64 + threadIdx.x;
    if (gid >= NG) return;

    constexpr int PC[NPAIR] = {0,0,0,0,0,1,1,1,1,2,2,2,3,3,4};
    constexpr int PE[NPAIR] = {1,2,3,4,5,2,3,4,5,3,4,5,4,5,5};
    constexpr int QIDX[NC][NC] = {
        {-1, 0, 1, 2, 3, 4},
        {-1,-1, 5, 6, 7, 8},
        {-1,-1,-1, 9,10,11},
        {-1,-1,-1,-1,12,13},
        {-1,-1,-1,-1,-1,14},
        {-1,-1,-1,-1,-1,-1}};

    // 8 partial rows: (chunk 0..3) x (parity s,n)
    const float* p0 = wsp + (8 * gid) * PSTR;
    float fs[NACCS], fn[NACCS];
    #pragma unroll
    for (int i = 0; i < NACCS; i++) {
        fs[i] = (p0[0 * PSTR + i] + p0[2 * PSTR + i]) + (p0[4 * PSTR + i] + p0[6 * PSTR + i]);
        fn[i] = (p0[1 * PSTR + i] + p0[3 * PSTR + i]) + (p0[5 * PSTR + i] + p0[7 * PSTR + i]);
    }
    // Reassemble the verified fin[74] layout
    float fin[NACC];
    #pragma unroll
    for (int c = 0; c < NC; c++) { fin[c] = fs[c]; fin[6 + c] = fn[c]; }
    #pragma unroll
    for (int q = 0; q < NPAIR; q++) {
        fin[12 + 4 * q + 0] = fs[6 + 2 * q];
        fin[12 + 4 * q + 1] = fs[6 + 2 * q + 1];
        fin[12 + 4 * q + 2] = fn[6 + 2 * q];
        fin[12 + 4 * q + 3] = fn[6 + 2 * q + 1];
    }
    fin[72] = fs[36];
    fin[73] = fn[36];

    const float invS = 1.f / (fin[72] + 1e-15f);
    const float invN = 1.f / (fin[73] + 1e-15f);

    // A = normalized psd_n + eps*I
    float Ar[NC][NC], Ai[NC][NC];
    #pragma unroll
    for (int c = 0; c < NC; c++) { Ar[c][c] = fin[6 + c] * invN; Ai[c][c] = 0.f; }
    #pragma unroll
    for (int q = 0; q < NPAIR; q++) {
        const int c = PC[q], e = PE[q];
        const float nre = fin[12 + 4 * q + 2] * invN;
        const float nim = fin[12 + 4 * q + 3] * invN;
        Ar[c][e] = nre;  Ai[c][e] = nim;
        Ar[e][c] = nre;  Ai[e][c] = -nim;
    }
    {
        float trn = 0.f;
        #pragma unroll
        for (int c = 0; c < NC; c++) trn += Ar[c][c];
        const float eps = trn * 1e-7f + 1e-8f;
        #pragma unroll
        for (int c = 0; c < NC; c++) Ar[c][c] += eps;
    }

    // In-place unpivoted LU: L (unit diag) below, U on/above.
    #pragma unroll
    for (int k = 0; k < NC; k++) {
        const float dr = Ar[k][k], di = Ai[k][k];
        const float idn = 1.f / (dr * dr + di * di);
        const float pr = dr * idn, pi = -di * idn;
        #pragma unroll
        for (int i = k + 1; i < NC; i++) {
            const float lr = Ar[i][k] * pr - Ai[i][k] * pi;
            const float li = Ar[i][k] * pi + Ai[i][k] * pr;
            Ar[i][k] = lr; Ai[i][k] = li;
            #pragma unroll
            for (int j = k + 1; j < NC; j++) {
                Ar[i][j] -= lr * Ar[k][j] - li * Ai[k][j];
                Ai[i][j] -= lr * Ai[k][j] + li * Ar[k][j];
            }
        }
    }

    // Column-by-column solve of A x = b_j (b_j = col j of normalized psd_s).
    float trr = 1e-8f, tri = 0.f;   // TIK_EPS on real part of trace
    float w0r[NC], w0i[NC];
    #pragma unroll
    for (int j = 0; j < NC; j++) {
        float xr[NC], xi[NC];
        #pragma unroll
        for (int i = 0; i < NC; i++) {
            if (i == j)      { xr[i] = fin[j] * invS;                      xi[i] = 0.f; }
            else if (i < j)  { const int q = QIDX[i][j];
                               xr[i] = fin[12 + 4 * q] * invS;  xi[i] =  fin[13 + 4 * q] * invS; }
            else             { const int q = QIDX[j][i];
                               xr[i] = fin[12 + 4 * q] * invS;  xi[i] = -fin[13 + 4 * q] * invS; }
        }
        #pragma unroll
        for (int i = 1; i < NC; i++) {
            #pragma unroll
            for (int k = 0; k < NC - 1; k++) if (k < i) {
                xr[i] -= Ar[i][k] * xr[k] - Ai[i][k] * xi[k];
                xi[i] -= Ar[i][k] * xi[k] + Ai[i][k] * xr[k];
            }
        }
        #pragma unroll
        for (int i = NC - 1; i >= 0; i--) {
            #pragma unroll
            for (int k = 0; k < NC; k++) if (k > i) {
                xr[i] -= Ar[i][k] * xr[k] - Ai[i][k] * xi[k];
                xi[i] -= Ar[i][k] * xi[k] + Ai[i][k] * xr[k];
            }
            const float dr = Ar[i][i], di = Ai[i][i];
            const float idn = 1.f / (dr * dr + di * di);
            const float pr = dr * idn, pi = -di * idn;
            const float tr0 = xr[i] * pr - xi[i] * pi;
            xi[i] = xr[i] * pi + xi[i] * pr;
            xr[i] = tr0;
        }
        trr += xr[j]; tri += xi[j];
        if (j == 0) {
            #pragma unroll
            for (int i = 0; i < NC; i++) { w0r[i] = xr[i]; w0i[i] = xi[i]; }
        }
    }

    const float idn = 1.f / (trr * trr + tri * tri);
    #pragma unroll
    for (int c = 0; c < NC; c++) {
        const float wre = (w0r[c] * trr + w0i[c] * tri) * idn;
        const float wim = (w0i[c] * trr - w0r[c] * tri) * idn;
        wsw[gid * 12 + c]     = wre;    // conj(w): real
        wsw[gid * 12 + 6 + c] = -wim;   // conj(w): imag
    }
}

// ---------------- Kernel C: enh[t] = sum_c conj(w[c]) * spec[c,t] -----------
// Round-5 float4 version (12 dwordx4 loads / 4 t per thread), 2056 blocks.
#define ACHUNK 2
#define ATCH (NT / ACHUNK)   // 1000 t per apply chunk
#define ANP4 (ATCH / 4)      // 250 float4 positions
#define CS4 (CS / 4)

__global__ __launch_bounds__(BLK) void apply_kernel(
    const float* __restrict__ sr, const float* __restrict__ si,
    const float* __restrict__ wsw, float* __restrict__ out)
{
    const int bx = blockIdx.x;
    const int g  = bx >> 1;
    const int b  = g / NF;
    const int f  = g - b * NF;
    const int tb = (bx & 1) * ATCH;
    const int sbase = b * NC * CS + f * NT + tb;

    const nfloat4* s4r = (const nfloat4*)(sr + sbase);
    const nfloat4* s4i = (const nfloat4*)(si + sbase);

    float wr[NC], wi[NC];
    #pragma unroll
    for (int c = 0; c < NC; c++) {
        wr[c] = wsw[g * 12 + c];
        wi[c] = wsw[g * 12 + 6 + c];
    }

    nfloat4* o4 = (nfloat4*)(out + 2 * (g * NT + tb));

    const int p = threadIdx.x;
    if (p < ANP4) {
        float rr[NC][4], ii[NC][4];
        #pragma unroll
        for (int c = 0; c < NC; c++) {
            const nfloat4 tr = s4r[c * CS4 + p];
            rr[c][0] = tr.x; rr[c][1] = tr.y; rr[c][2] = tr.z; rr[c][3] = tr.w;
            const nfloat4 ti = s4i[c * CS4 + p];
            ii[c][0] = ti.x; ii[c][1] = ti.y; ii[c][2] = ti.z; ii[c][3] = ti.w;
        }
        float er[4], ei[4];
        #pragma unroll
        for (int k = 0; k < 4; k++) {
            float a = 0.f, bb = 0.f;
            #pragma unroll
            for (int c = 0; c < NC; c++) {
                a  += wr[c] * rr[c][k] - wi[c] * ii[c][k];
                bb += wr[c] * ii[c][k] + wi[c] * rr[c][k];
            }
            er[k] = a; ei[k] = bb;
        }
        nfloat4 o0 = {er[0], ei[0], er[1], ei[1]};
        nfloat4 o1 = {er[2], ei[2], er[3], ei[3]};
        __builtin_nontemporal_store(o0, &o4[2 * p]);
        __builtin_nontemporal_store(o1, &o4[2 * p + 1]);
    }
}

extern "C" void kernel_launch(void* const* d_in, const int* in_sizes, int n_in,
                              void* d_out, int out_size, void* d_ws, size_t ws_size,
                              hipStream_t stream) {
    const float* sr = (const float*)d_in[0];
    const float* si = (const float*)d_in[1];
    const float* ms = (const float*)d_in[2];
    const float* mn = (const float*)d_in[3];
    float* out = (float*)d_out;

    float* wsp = (float*)d_ws;                       // [NG*8][PSTR] split partials
    float* wsw = wsp + NG * 8 * PSTR;                // [NG][12] conj(w)

    psd_kernel<<<NG * NCHUNK * 2, BLK, 0, stream>>>(sr, si, ms, mn, wsp);
    solve_kernel<<<(NG + 63) / 64, 64, 0, stream>>>(wsp, wsw);
    apply_kernel<<<NG * ACHUNK, BLK, 0, stream>>>(sr, si, wsw, out);
}

// Round 7
// 162.259 us; speedup vs baseline: 1.0750x; 1.0750x over previous
//
#include <hip/hip_runtime.h>

#define NB 4
#define NC 6
#define NF 257
#define NT 2000
#define NG (NB * NF)        // 1028 (b,f) groups
#define NPAIR 15
#define NACC 74             // wsp row: [0..5] s_diag, [6..11] n_diag, [12+4q..] s_re,s_im,n_re,n_im, [72] sum_ms, [73] sum_mn
#define NACCS 37            // per-pass regs: [0..5] diag, [6+2q],[7+2q] pair re/im, [36] mask sum
#define NCHUNK 4
#define TCH (NT / NCHUNK)   // 500 t per chunk
#define NP2 (TCH / 2)       // 250 float2 positions per chunk
#define BLK 256
#define CS  (NF * NT)       // channel stride (floats)
#define CS2 (CS / 2)        // channel stride (float2)

typedef float nfloat4 __attribute__((ext_vector_type(4)));

// DPP row-shift-right add: lane i += lane (i-N) within its 16-lane row
// (0 beyond row edge). After shr8+shr4+shr2: lane14 = row evens-sum,
// lane15 = row odds-sum (HW-verified in prior session).
template<int CTRL>
__device__ __forceinline__ float dpp_add(float v) {
    int s = __builtin_amdgcn_update_dpp(0, __builtin_bit_cast(int, v), CTRL, 0xF, 0xF, true);
    return v + __builtin_bit_cast(float, s);
}

// One mask pass: accumulate 37 stats from the already-loaded spec values,
// DPP-reduce, write into this pass's columns of red[32][74].
// PAR=0 -> s-mask columns, PAR=1 -> n-mask columns.
// 37 accs live only inside this function -> register reuse across passes.
template<int PAR>
__device__ __forceinline__ void psd_pass(
    const float wm[2], const float rr[NC][2], const float ii[NC][2],
    float (*red)[NACC], int tid)
{
    constexpr int PC[NPAIR] = {0,0,0,0,0,1,1,1,1,2,2,2,3,3,4};
    constexpr int PE[NPAIR] = {1,2,3,4,5,2,3,4,5,3,4,5,4,5,5};

    float acc[NACCS];
    #pragma unroll
    for (int i = 0; i < NACCS; i++) acc[i] = 0.f;

    #pragma unroll
    for (int k = 0; k < 2; k++) acc[36] += wm[k];
    #pragma unroll
    for (int c = 0; c < NC; c++) {
        #pragma unroll
        for (int k = 0; k < 2; k++) {
            const float d = rr[c][k] * rr[c][k] + ii[c][k] * ii[c][k];
            acc[c] += d * wm[k];
        }
    }
    #pragma unroll
    for (int q = 0; q < NPAIR; q++) {
        const int c = PC[q], e = PE[q];
        #pragma unroll
        for (int k = 0; k < 2; k++) {
            const float cr = rr[c][k] * rr[e][k] + ii[c][k] * ii[e][k];
            const float ci = ii[c][k] * rr[e][k] - rr[c][k] * ii[e][k];
            acc[6 + 2 * q]     += cr * wm[k];
            acc[6 + 2 * q + 1] += ci * wm[k];
        }
    }

    // In-row DPP reduction: lane14 = row evens-sum, lane15 = odds.
    #pragma unroll
    for (int i = 0; i < NACCS; i++) {
        float v = acc[i];
        v = dpp_add<0x118>(v);   // row_shr:8
        v = dpp_add<0x114>(v);   // row_shr:4
        v = dpp_add<0x112>(v);   // row_shr:2
        acc[i] = v;
    }

    const int lane16 = tid & 15;
    const int ridx   = ((tid >> 4) << 1) | (lane16 & 1);  // 0..31
    if (lane16 >= 14) {
        #pragma unroll
        for (int c = 0; c < NC; c++) red[ridx][PAR ? 6 + c : c] = acc[c];
        #pragma unroll
        for (int q = 0; q < NPAIR; q++) {
            red[ridx][12 + 4 * q + 2 * PAR]     = acc[6 + 2 * q];
            red[ridx][12 + 4 * q + 2 * PAR + 1] = acc[6 + 2 * q + 1];
        }
        red[ridx][72 + PAR] = acc[36];
    }
}

// ---------------- Kernel A: raw weighted PSD partials per (group, chunk) ----
// Round-0 grid (4112 blocks, 1 float2/thread, one 14-load burst) but the two
// mask passes run SEQUENTIALLY reusing one 37-reg accumulator set: round-6's
// low VGPR (-> high occupancy) at round-0's single spec read (no HBM double-
// fetch). sched_barrier(0) between passes stops the compiler from re-fusing
// them (which would re-inflate pressure to 74 live accs).
__global__ __launch_bounds__(BLK) void psd_kernel(
    const float* __restrict__ sr, const float* __restrict__ si,
    const float* __restrict__ ms, const float* __restrict__ mn,
    float* __restrict__ wsp)
{
    const int bx = blockIdx.x;
    const int g  = bx >> 2;
    const int b  = g / NF;
    const int f  = g - b * NF;
    const int tb = (bx & 3) * TCH;
    const int sbase = b * NC * CS + f * NT + tb;
    const int mbase = g * NT + tb;
    const int tid = threadIdx.x;

    const float2* s2r = (const float2*)(sr + sbase);
    const float2* s2i = (const float2*)(si + sbase);
    const float2* m2s = (const float2*)(ms + mbase);
    const float2* m2n = (const float2*)(mn + mbase);

    __shared__ float red[32][NACC];

    // Unconditional load burst; inactive lanes load p=0 and zero their mask
    // weights (every accumulator term carries a mask factor -> contributes 0).
    const bool act = tid < NP2;
    const int  p   = act ? tid : 0;

    float wms[2], wmn[2], rr[NC][2], ii[NC][2];
    {
        const float2 t0 = m2s[p];
        wms[0] = t0.x; wms[1] = t0.y;
        const float2 t1 = m2n[p];
        wmn[0] = t1.x; wmn[1] = t1.y;
    }
    #pragma unroll
    for (int c = 0; c < NC; c++) {
        const float2 tr = s2r[c * CS2 + p];
        rr[c][0] = tr.x; rr[c][1] = tr.y;
        const float2 ti = s2i[c * CS2 + p];
        ii[c][0] = ti.x; ii[c][1] = ti.y;
    }
    if (!act) { wms[0] = wms[1] = wmn[0] = wmn[1] = 0.f; }

    // Pass 1: s-mask stats (37 regs), then release them...
    psd_pass<0>(wms, rr, ii, red, tid);
    __builtin_amdgcn_sched_barrier(0);   // pin ordering: pass-2 must not hoist
    // Pass 2: n-mask stats reusing the same accumulator registers.
    psd_pass<1>(wmn, rr, ii, red, tid);

    __syncthreads();

    if (tid < NACC) {
        float s = 0.f;
        #pragma unroll
        for (int r = 0; r < 32; r++) s += red[r][tid];
        wsp[bx * NACC + tid] = s;
    }
}

// ---------------- Kernel B: one thread per (b,f) — LU + column solves -------
// Verbatim round-0 verified solve (4 partial rows). launch_bounds(64,1):
// high VGPR allowed so nothing spills.
__global__ __launch_bounds__(64, 1) void solve_kernel(
    const float* __restrict__ wsp, float* __restrict__ wsw)
{
    const int gid = blockIdx.x * 64 + threadIdx.x;
    if (gid >= NG) return;

    constexpr int PC[NPAIR] = {0,0,0,0,0,1,1,1,1,2,2,2,3,3,4};
    constexpr int PE[NPAIR] = {1,2,3,4,5,2,3,4,5,3,4,5,4,5,5};
    constexpr int QIDX[NC][NC] = {
        {-1, 0, 1, 2, 3, 4},
        {-1,-1, 5, 6, 7, 8},
        {-1,-1,-1, 9,10,11},
        {-1,-1,-1,-1,12,13},
        {-1,-1,-1,-1,-1,14},
        {-1,-1,-1,-1,-1,-1}};

    const float* p0 = wsp + (NCHUNK * gid) * NACC;
    float fin[NACC];
    #pragma unroll
    for (int i = 0; i < NACC; i++)
        fin[i] = (p0[i] + p0[NACC + i]) + (p0[2 * NACC + i] + p0[3 * NACC + i]);

    const float invS = 1.f / (fin[72] + 1e-15f);
    const float invN = 1.f / (fin[73] + 1e-15f);

    // A = normalized psd_n + eps*I
    float Ar[NC][NC], Ai[NC][NC];
    #pragma unroll
    for (int c = 0; c < NC; c++) { Ar[c][c] = fin[6 + c] * invN; Ai[c][c] = 0.f; }
    #pragma unroll
    for (int q = 0; q < NPAIR; q++) {
        const int c = PC[q], e = PE[q];
        const float nre = fin[12 + 4 * q + 2] * invN;
        const float nim = fin[12 + 4 * q + 3] * invN;
        Ar[c][e] = nre;  Ai[c][e] = nim;
        Ar[e][c] = nre;  Ai[e][c] = -nim;
    }
    {
        float trn = 0.f;
        #pragma unroll
        for (int c = 0; c < NC; c++) trn += Ar[c][c];
        const float eps = trn * 1e-7f + 1e-8f;
        #pragma unroll
        for (int c = 0; c < NC; c++) Ar[c][c] += eps;
    }

    // In-place unpivoted LU: L (unit diag) below, U on/above.
    #pragma unroll
    for (int k = 0; k < NC; k++) {
        const float dr = Ar[k][k], di = Ai[k][k];
        const float idn = 1.f / (dr * dr + di * di);
        const float pr = dr * idn, pi = -di * idn;
        #pragma unroll
        for (int i = k + 1; i < NC; i++) {
            const float lr = Ar[i][k] * pr - Ai[i][k] * pi;
            const float li = Ar[i][k] * pi + Ai[i][k] * pr;
            Ar[i][k] = lr; Ai[i][k] = li;
            #pragma unroll
            for (int j = k + 1; j < NC; j++) {
                Ar[i][j] -= lr * Ar[k][j] - li * Ai[k][j];
                Ai[i][j] -= lr * Ai[k][j] + li * Ar[k][j];
            }
        }
    }

    // Column-by-column solve of A x = b_j (b_j = col j of normalized psd_s).
    float trr = 1e-8f, tri = 0.f;   // TIK_EPS on real part of trace
    float w0r[NC], w0i[NC];
    #pragma unroll
    for (int j = 0; j < NC; j++) {
        float xr[NC], xi[NC];
        #pragma unroll
        for (int i = 0; i < NC; i++) {
            if (i == j)      { xr[i] = fin[j] * invS;                      xi[i] = 0.f; }
            else if (i < j)  { const int q = QIDX[i][j];
                               xr[i] = fin[12 + 4 * q] * invS;  xi[i] =  fin[13 + 4 * q] * invS; }
            else             { const int q = QIDX[j][i];
                               xr[i] = fin[12 + 4 * q] * invS;  xi[i] = -fin[13 + 4 * q] * invS; }
        }
        #pragma unroll
        for (int i = 1; i < NC; i++) {
            #pragma unroll
            for (int k = 0; k < NC - 1; k++) if (k < i) {
                xr[i] -= Ar[i][k] * xr[k] - Ai[i][k] * xi[k];
                xi[i] -= Ar[i][k] * xi[k] + Ai[i][k] * xr[k];
            }
        }
        #pragma unroll
        for (int i = NC - 1; i >= 0; i--) {
            #pragma unroll
            for (int k = 0; k < NC; k++) if (k > i) {
                xr[i] -= Ar[i][k] * xr[k] - Ai[i][k] * xi[k];
                xi[i] -= Ar[i][k] * xi[k] + Ai[i][k] * xr[k];
            }
            const float dr = Ar[i][i], di = Ai[i][i];
            const float idn = 1.f / (dr * dr + di * di);
            const float pr = dr * idn, pi = -di * idn;
            const float tr0 = xr[i] * pr - xi[i] * pi;
            xi[i] = xr[i] * pi + xi[i] * pr;
            xr[i] = tr0;
        }
        trr += xr[j]; tri += xi[j];
        if (j == 0) {
            #pragma unroll
            for (int i = 0; i < NC; i++) { w0r[i] = xr[i]; w0i[i] = xi[i]; }
        }
    }

    const float idn = 1.f / (trr * trr + tri * tri);
    #pragma unroll
    for (int c = 0; c < NC; c++) {
        const float wre = (w0r[c] * trr + w0i[c] * tri) * idn;
        const float wim = (w0i[c] * trr - w0r[c] * tri) * idn;
        wsw[gid * 12 + c]     = wre;    // conj(w): real
        wsw[gid * 12 + 6 + c] = -wim;   // conj(w): imag
    }
}

// ---------------- Kernel C: enh[t] = sum_c conj(w[c]) * spec[c,t] -----------
// Round-5 float4 version: 12 dwordx4 loads / 4 t per thread, 2 nontemporal
// dwordx4 stores. 2056 blocks x 256 threads. Spec is L3-hot after psd.
#define ACHUNK 2
#define ATCH (NT / ACHUNK)   // 1000 t per apply chunk
#define ANP4 (ATCH / 4)      // 250 float4 positions
#define CS4 (CS / 4)

__global__ __launch_bounds__(BLK) void apply_kernel(
    const float* __restrict__ sr, const float* __restrict__ si,
    const float* __restrict__ wsw, float* __restrict__ out)
{
    const int bx = blockIdx.x;
    const int g  = bx >> 1;
    const int b  = g / NF;
    const int f  = g - b * NF;
    const int tb = (bx & 1) * ATCH;
    const int sbase = b * NC * CS + f * NT + tb;

    const nfloat4* s4r = (const nfloat4*)(sr + sbase);
    const nfloat4* s4i = (const nfloat4*)(si + sbase);

    float wr[NC], wi[NC];
    #pragma unroll
    for (int c = 0; c < NC; c++) {
        wr[c] = wsw[g * 12 + c];
        wi[c] = wsw[g * 12 + 6 + c];
    }

    nfloat4* o4 = (nfloat4*)(out + 2 * (g * NT + tb));

    const int p = threadIdx.x;
    if (p < ANP4) {
        float rr[NC][4], ii[NC][4];
        #pragma unroll
        for (int c = 0; c < NC; c++) {
            const nfloat4 tr = s4r[c * CS4 + p];
            rr[c][0] = tr.x; rr[c][1] = tr.y; rr[c][2] = tr.z; rr[c][3] = tr.w;
            const nfloat4 ti = s4i[c * CS4 + p];
            ii[c][0] = ti.x; ii[c][1] = ti.y; ii[c][2] = ti.z; ii[c][3] = ti.w;
        }
        float er[4], ei[4];
        #pragma unroll
        for (int k = 0; k < 4; k++) {
            float a = 0.f, bb = 0.f;
            #pragma unroll
            for (int c = 0; c < NC; c++) {
                a  += wr[c] * rr[c][k] - wi[c] * ii[c][k];
                bb += wr[c] * ii[c][k] + wi[c] * rr[c][k];
            }
            er[k] = a; ei[k] = bb;
        }
        nfloat4 o0 = {er[0], ei[0], er[1], ei[1]};
        nfloat4 o1 = {er[2], ei[2], er[3], ei[3]};
        __builtin_nontemporal_store(o0, &o4[2 * p]);
        __builtin_nontemporal_store(o1, &o4[2 * p + 1]);
    }
}

extern "C" void kernel_launch(void* const* d_in, const int* in_sizes, int n_in,
                              void* d_out, int out_size, void* d_ws, size_t ws_size,
                              hipStream_t stream) {
    const float* sr = (const float*)d_in[0];
    const float* si = (const float*)d_in[1];
    const float* ms = (const float*)d_in[2];
    const float* mn = (const float*)d_in[3];
    float* out = (float*)d_out;

    float* wsp = (float*)d_ws;                       // [NG*NCHUNK][NACC] partials
    float* wsw = wsp + NG * NCHUNK * NACC;           // [NG][12] conj(w)

    psd_kernel<<<NG * NCHUNK, BLK, 0, stream>>>(sr, si, ms, mn, wsp);
    solve_kernel<<<(NG + 63) / 64, 64, 0, stream>>>(wsp, wsw);
    apply_kernel<<<NG * ACHUNK, BLK, 0, stream>>>(sr, si, wsw, out);
}